// Round 14
// baseline (19.331 us; speedup 1.0000x reference)
//
#include <hip/hip_runtime.h>
#include <math.h>

#define NN    1000
#define NPAD  1024
#define NTILE 32              /* 32 n-tiles of 32 gaussians                 */
#define TPW   8               /* tiles per wave (4 n-chunks of 256)         */
#define LOG2E 1.4426950408889634f
#define LOG2_2PI 2.6514961294723187f   /* log2(2*pi) */
#define SKIP_THR (-24.2f)     /* e<2^-24 truncates to f16 0 (cvt_pkrtz=RTZ) */

typedef float        f32x4  __attribute__((ext_vector_type(4)));
typedef _Float16     f16x8  __attribute__((ext_vector_type(8)));
typedef unsigned int u32x4v __attribute__((ext_vector_type(4)));

static __device__ __forceinline__ float ex2(float x)  { return __builtin_amdgcn_exp2f(x); }
static __device__ __forceinline__ float lg2(float x)  { return __builtin_amdgcn_logf(x); }
static __device__ __forceinline__ float rcp_(float x) { return __builtin_amdgcn_rcpf(x); }
static __device__ __forceinline__ float fsig(float x) { return rcp_(1.f + ex2(-LOG2E * x)); }
// tanh(x) = 1 - 2/(exp2(2*log2e*x)+1); pass 2*log2e*x
static __device__ __forceinline__ float ftanh2x(float two_x_log2e) {
    return 1.f - 2.f * rcp_(ex2(two_x_log2e) + 1.f);
}
// e = exp2(K - u^2), u = p*x + t
static __device__ __forceinline__ float ev2(float p, float t, float K, float x) {
    float u = fmaf(p, x, t);
    return ex2(fmaf(-u, u, K));
}
static __device__ __forceinline__ unsigned pk2(float a, float b) {
    return __builtin_bit_cast(unsigned, __builtin_amdgcn_cvt_pkrtz(a, b));
}

// ============ fused kernel: ONE IMAGE ROW per block (256 px, 16 waves) =====
// phase 0a: 1 gaussian/thread -> row-folded params (p, t, K') to LDS
// phase 0b: B-fragments (sigmoid alpha|rgb -> f16)
// phase 0c: analytic (tile x 16px-group) max bounds -> skip table + EPS term
// pass C:   raw e = exp2(K' - u^2), f16 MFMA accumulate, wave-uniform skips
// epilogue: out = C_rgb / (C_alpha + EPS * 2^Mq)
__global__ __launch_bounds__(1024, 4) void splat_fused(
    const float* __restrict__ rho, const float* __restrict__ sigma,
    const float* __restrict__ coords, const float* __restrict__ alpha,
    const float* __restrict__ colors, float* __restrict__ out)
{
    __shared__ f32x4  Lp4[NPAD/4], Lt4[NPAD/4], Lk4[NPAD/4];  // 12 KB
    __shared__ u32x4v Lbf[NTILE][4][4];                       //  8 KB
    __shared__ float  pm2[64][16];                            //  4 KB
    __shared__ float  Lbnd[NTILE][16];                        //  2 KB
    __shared__ float  pmg[16];
    __shared__ f32x4  pc4[16][64];                            // 16 KB

    const int tid  = threadIdx.x;
    const int wave = tid >> 6, lane = tid & 63;
    const int col  = lane & 15, g = lane >> 4;
    const int nchunk = wave & 3, pxq = wave >> 2;   // n-chunk x pixel-quad
    const int row  = blockIdx.x;
    const float step = 2.0f / 255.0f;
    const float y  = -1.0f + (float)row * step;                 // block-uniform
    const float xb = -1.0f + (float)(64*pxq + col) * step;
    const float x0 = xb, x1 = xb + 16.f*step, x2 = xb + 32.f*step, x3 = xb + 48.f*step;

    // ---- phase 0a: one gaussian per thread (native transcendentals) ----
    float* Lp = (float*)Lp4; float* Lt = (float*)Lt4; float* Lk = (float*)Lk4;
    {
        const int n = tid;
        float p, q, r_, u0, v0, K;
        if (n >= NN) { p=q=r_=u0=v0=0.f; K=-1e30f; }   // dummy: contributes 0
        else {
            float sx = ftanh2x(LOG2E * sigma[2*n])   + 1e-4f;  // tanh(s/2)
            float sy = ftanh2x(LOG2E * sigma[2*n+1]) + 1e-4f;
            float ra = fsig(rho[n]) + 1e-6f;
            float cxx = sx*sx + 1e-6f, cyy = sy*sy + 1e-6f;
            float cxy = sx*sy*ra;
            float det = cxx*cyy - cxy*cxy;
            float invdet = rcp_(det);
            float hl = 0.5f * LOG2E;
            p  = sqrtf(hl * cyy * invdet);
            q  = (-hl * cxy * invdet) * rcp_(p);
            r_ = sqrtf(hl * rcp_(cyy));      // exact: b - q^2 = hl/cyy
            float cx = ftanh2x((2.f*LOG2E) * coords[2*n])   - 0.5f;
            float cy = ftanh2x((2.f*LOG2E) * coords[2*n+1]) - 0.5f;
            u0 = p*cx + q*cy;
            v0 = r_*cy;
            K  = 0.5f * lg2(det + 1e-6f) - LOG2_2PI;
        }
        float t = fmaf(q, y, u0);
        float v = fmaf(r_, y, v0);
        Lp[tid] = p; Lt[tid] = t; Lk[tid] = fmaf(-v, v, K);
    }
    // ---- phase 0b: B-fragments, one slot per thread (tid < 512) ----
    if (tid < 512) {                         // slot: T(32) x c(4) x g2(4)
        int T = tid >> 4, c = (tid >> 2) & 3, g2 = tid & 3;
        unsigned w[4] = {0u,0u,0u,0u};
        #pragma unroll
        for (int j = 0; j < 8; ++j) {
            int n = T*32 + g2*8 + j;
            float act = 0.f;
            if (n < NN)
                act = fsig((c == 0) ? alpha[n] : colors[3*n + c - 1]);
            unsigned short us = __builtin_bit_cast(unsigned short, (_Float16)act);
            w[j>>1] |= (unsigned)us << (16*(j&1));
        }
        Lbf[T][c][g2] = (u32x4v){w[0], w[1], w[2], w[3]};
    }
    __syncthreads();

    // preload this wave's B-fragments (n-chunk owns tiles nchunk*8 .. +7)
    u32x4v BfR[TPW];
    #pragma unroll
    for (int t = 0; t < TPW; ++t)
        BfR[t] = (col < 4) ? Lbf[nchunk*TPW + t][col][g] : (u32x4v){0u,0u,0u,0u};

    // ---- phase 0c: analytic group-max. thread = (16-g chunk) x (16px group) ----
    // max_{x in [xlo,xhi]} (K' - (p*x+t)^2) = K' - (ulo*uhi>0 ? min(ulo^2,uhi^2) : 0)
    {
        const int q16 = tid & 15, chunk = tid >> 4;
        const float xlo = -1.0f + (float)(16*q16) * step;
        const float xhi = xlo + 15.f*step;
        const int nb = chunk * 16;
        float mx = -3.0e38f;
        #pragma unroll
        for (int i = 0; i < 16; ++i) {
            float p = Lp[nb+i], t = Lt[nb+i], Kp = Lk[nb+i];
            float ulo = fmaf(p, xlo, t);
            float uhi = fmaf(p, xhi, t);
            float pen = (ulo*uhi > 0.f) ? fminf(ulo*ulo, uhi*uhi) : 0.f;
            mx = fmaxf(mx, Kp - pen);
        }
        pm2[chunk][q16] = mx;
    }
    __syncthreads();
    if (tid < 512) {                         // (tile,group) skip bounds
        int T = tid >> 4, q = tid & 15;
        Lbnd[T][q] = fmaxf(pm2[2*T][q], pm2[2*T+1][q]);
    }
    if (tid < 16) {                          // stage 2: 64 partials -> EPS term
        float M = -3.0e38f;
        #pragma unroll
        for (int j = 0; j < 64; ++j) M = fmaxf(M, pm2[j][tid]);
        pmg[tid] = 1e-6f * ex2(M);           // EPS * 2^Mq  (ref-equivalent EPS)
    }
    __syncthreads();

    const int nbase = nchunk*256 + g*8;
    const int G0 = pxq * 4;

    // ---- pass C: raw e = exp2(K' - u^2), MFMA accumulate, uniform skips ----
    f32x4 C0 = {0.f,0.f,0.f,0.f}, C1 = {0.f,0.f,0.f,0.f};
    f32x4 C2 = {0.f,0.f,0.f,0.f}, C3 = {0.f,0.f,0.f,0.f};
    for (int t = 0; t < TPW; ++t) {
        const int Tt = nchunk*TPW + t;       // wave-uniform tile index
        float b0 = Lbnd[Tt][G0+0], b1 = Lbnd[Tt][G0+1];
        float b2 = Lbnd[Tt][G0+2], b3 = Lbnd[Tt][G0+3];
        // whole (tile x 64px) dead: skip loads too (bitwise no-op: all e
        // would truncate to f16 zero under RTZ, MFMA would add exact 0)
        if (fmaxf(fmaxf(b0, b1), fmaxf(b2, b3)) < SKIP_THR) continue;

        int q4 = (nbase + t*32) >> 2;
        f32x4 pa = Lp4[q4], pb = Lp4[q4+1];
        f32x4 ta = Lt4[q4], tb = Lt4[q4+1];
        f32x4 ka = Lk4[q4], kb = Lk4[q4+1];
        f16x8 Bf = __builtin_bit_cast(f16x8, BfR[t]);

        u32x4v W;
        if (b0 >= SKIP_THR) {
            W = (u32x4v){ pk2(ev2(pa[0],ta[0],ka[0],x0), ev2(pa[1],ta[1],ka[1],x0)),
                          pk2(ev2(pa[2],ta[2],ka[2],x0), ev2(pa[3],ta[3],ka[3],x0)),
                          pk2(ev2(pb[0],tb[0],kb[0],x0), ev2(pb[1],tb[1],kb[1],x0)),
                          pk2(ev2(pb[2],tb[2],kb[2],x0), ev2(pb[3],tb[3],kb[3],x0)) };
            C0 = __builtin_amdgcn_mfma_f32_16x16x32_f16(__builtin_bit_cast(f16x8, W), Bf, C0, 0, 0, 0);
        }
        if (b1 >= SKIP_THR) {
            W = (u32x4v){ pk2(ev2(pa[0],ta[0],ka[0],x1), ev2(pa[1],ta[1],ka[1],x1)),
                          pk2(ev2(pa[2],ta[2],ka[2],x1), ev2(pa[3],ta[3],ka[3],x1)),
                          pk2(ev2(pb[0],tb[0],kb[0],x1), ev2(pb[1],tb[1],kb[1],x1)),
                          pk2(ev2(pb[2],tb[2],kb[2],x1), ev2(pb[3],tb[3],kb[3],x1)) };
            C1 = __builtin_amdgcn_mfma_f32_16x16x32_f16(__builtin_bit_cast(f16x8, W), Bf, C1, 0, 0, 0);
        }
        if (b2 >= SKIP_THR) {
            W = (u32x4v){ pk2(ev2(pa[0],ta[0],ka[0],x2), ev2(pa[1],ta[1],ka[1],x2)),
                          pk2(ev2(pa[2],ta[2],ka[2],x2), ev2(pa[3],ta[3],ka[3],x2)),
                          pk2(ev2(pb[0],tb[0],kb[0],x2), ev2(pb[1],tb[1],kb[1],x2)),
                          pk2(ev2(pb[2],tb[2],kb[2],x2), ev2(pb[3],tb[3],kb[3],x2)) };
            C2 = __builtin_amdgcn_mfma_f32_16x16x32_f16(__builtin_bit_cast(f16x8, W), Bf, C2, 0, 0, 0);
        }
        if (b3 >= SKIP_THR) {
            W = (u32x4v){ pk2(ev2(pa[0],ta[0],ka[0],x3), ev2(pa[1],ta[1],ka[1],x3)),
                          pk2(ev2(pa[2],ta[2],ka[2],x3), ev2(pa[3],ta[3],ka[3],x3)),
                          pk2(ev2(pb[0],tb[0],kb[0],x3), ev2(pb[1],tb[1],kb[1],x3)),
                          pk2(ev2(pb[2],tb[2],kb[2],x3), ev2(pb[3],tb[3],kb[3],x3)) };
            C3 = __builtin_amdgcn_mfma_f32_16x16x32_f16(__builtin_bit_cast(f16x8, W), Bf, C3, 0, 0, 0);
        }
    }

    // ---- epilogue: per-pixel sum over the 4 n-chunks ----
    if (col < 4) {
        float* pcf = (float*)pc4;
        #pragma unroll
        for (int i = 0; i < 4; ++i) {        // C layout: col=ch, row=4g+i
            int r0 = 4*g + i;
            pcf[(wave*64 + r0     )*4 + col] = C0[i];
            pcf[(wave*64 + r0 + 16)*4 + col] = C1[i];
            pcf[(wave*64 + r0 + 32)*4 + col] = C2[i];
            pcf[(wave*64 + r0 + 48)*4 + col] = C3[i];
        }
    }
    __syncthreads();
    if (tid < 256) {
        int px = tid;
        int pq = px >> 6, l = px & 63;
        f32x4 S = pc4[4*pq+0][l] + pc4[4*pq+1][l] + pc4[4*pq+2][l] + pc4[4*pq+3][l];
        float inv = 1.0f / (S[0] + pmg[px >> 4]);   // S: (alpha, r, g, b)
        int o = (row*256 + px) * 3;
        out[o] = S[1]*inv; out[o+1] = S[2]*inv; out[o+2] = S[3]*inv;
    }
}

extern "C" void kernel_launch(void* const* d_in, const int* in_sizes, int n_in,
                              void* d_out, int out_size, void* d_ws, size_t ws_size,
                              hipStream_t stream) {
    const float* rho    = (const float*)d_in[0];
    const float* sigma  = (const float*)d_in[1];
    const float* coords = (const float*)d_in[2];
    const float* alpha  = (const float*)d_in[3];
    const float* colors = (const float*)d_in[4];
    float* out = (float*)d_out;   // xy derived analytically (validated r8)

    // 256 rows -> 256 blocks x 1024 threads = exactly 1 block/CU
    splat_fused<<<256, 1024, 0, stream>>>(rho, sigma, coords, alpha, colors, out);
}

// Round 15
// 17.849 us; speedup vs baseline: 1.0830x; 1.0830x over previous
//
#include <hip/hip_runtime.h>
#include <math.h>

#define NN    1000
#define NPAD  1024
#define NTILE 32              /* 32 n-tiles of 32 gaussians                 */
#define TPW   8               /* tiles per wave (4 n-chunks of 256)         */
#define LOG2E 1.4426950408889634f
#define LOG2_2PI 2.6514961294723187f   /* log2(2*pi) */

typedef float        f32x4  __attribute__((ext_vector_type(4)));
typedef _Float16     f16x8  __attribute__((ext_vector_type(8)));
typedef unsigned int u32x4v __attribute__((ext_vector_type(4)));

static __device__ __forceinline__ float ex2(float x)  { return __builtin_amdgcn_exp2f(x); }
static __device__ __forceinline__ float lg2(float x)  { return __builtin_amdgcn_logf(x); }
static __device__ __forceinline__ float rcp_(float x) { return __builtin_amdgcn_rcpf(x); }
// native sigmoid / tanh (1-ulp-class; output path is f16 so plenty accurate)
static __device__ __forceinline__ float fsig(float x) { return rcp_(1.f + ex2(-LOG2E * x)); }
// tanh(x) = 1 - 2/(exp2(2*log2e*x)+1); pass 2*log2e*x
static __device__ __forceinline__ float ftanh2x(float two_x_log2e) {
    return 1.f - 2.f * rcp_(ex2(two_x_log2e) + 1.f);
}
// e = exp2(K - u^2), u = p*x + t   (2 FMA + exp2; NO max subtraction)
static __device__ __forceinline__ float ev2(float p, float t, float K, float x) {
    float u = fmaf(p, x, t);
    return ex2(fmaf(-u, u, K));
}
static __device__ __forceinline__ unsigned pk2(float a, float b) {
    return __builtin_bit_cast(unsigned, __builtin_amdgcn_cvt_pkrtz(a, b));
}

// ============ fused kernel: ONE IMAGE ROW per block (256 px, 16 waves) =====
// phase 0a: 1 gaussian/thread -> row-folded params (p, t, K') to LDS
// phase 0b: B-fragments (sigmoid alpha|rgb -> f16)
// phase 0c: per-16px-group analytic max bound (epilogue EPS term ONLY)
// pass C:   raw e = exp2(K' - u^2), f16 MFMA accumulate (alpha,r,g,b)
// epilogue: out = C_rgb / (C_alpha + EPS * 2^Mq)
__global__ __launch_bounds__(1024, 4) void splat_fused(
    const float* __restrict__ rho, const float* __restrict__ sigma,
    const float* __restrict__ coords, const float* __restrict__ alpha,
    const float* __restrict__ colors, float* __restrict__ out)
{
    __shared__ f32x4  Lp4[NPAD/4], Lt4[NPAD/4], Lk4[NPAD/4];  // 12 KB
    __shared__ u32x4v Lbf[NTILE][4][4];                       //  8 KB
    __shared__ float  pm2[64][16];                            //  4 KB
    __shared__ float  pmg[16];
    __shared__ f32x4  pc4[16][64];                            // 16 KB

    const int tid  = threadIdx.x;
    const int wave = tid >> 6, lane = tid & 63;
    const int col  = lane & 15, g = lane >> 4;
    const int nchunk = wave & 3, pxq = wave >> 2;   // n-chunk x pixel-quad
    const int row  = blockIdx.x;
    const float step = 2.0f / 255.0f;
    const float y  = -1.0f + (float)row * step;                 // block-uniform
    const float xb = -1.0f + (float)(64*pxq + col) * step;
    const float x0 = xb, x1 = xb + 16.f*step, x2 = xb + 32.f*step, x3 = xb + 48.f*step;

    // ---- phase 0a: one gaussian per thread (native transcendentals) ----
    float* Lp = (float*)Lp4; float* Lt = (float*)Lt4; float* Lk = (float*)Lk4;
    {
        const int n = tid;
        float p, q, r_, u0, v0, K;
        if (n >= NN) { p=q=r_=u0=v0=0.f; K=-1e30f; }   // dummy: contributes 0
        else {
            float sx = ftanh2x(LOG2E * sigma[2*n])   + 1e-4f;  // tanh(s/2)
            float sy = ftanh2x(LOG2E * sigma[2*n+1]) + 1e-4f;
            float ra = fsig(rho[n]) + 1e-6f;
            float cxx = sx*sx + 1e-6f, cyy = sy*sy + 1e-6f;
            float cxy = sx*sy*ra;
            float det = cxx*cyy - cxy*cxy;
            float invdet = rcp_(det);
            float hl = 0.5f * LOG2E;
            p  = sqrtf(hl * cyy * invdet);
            q  = (-hl * cxy * invdet) * rcp_(p);
            r_ = sqrtf(hl * rcp_(cyy));      // exact: b - q^2 = hl/cyy
            float cx = ftanh2x((2.f*LOG2E) * coords[2*n])   - 0.5f;
            float cy = ftanh2x((2.f*LOG2E) * coords[2*n+1]) - 0.5f;
            u0 = p*cx + q*cy;
            v0 = r_*cy;
            K  = 0.5f * lg2(det + 1e-6f) - LOG2_2PI;
        }
        float t = fmaf(q, y, u0);
        float v = fmaf(r_, y, v0);
        Lp[tid] = p; Lt[tid] = t; Lk[tid] = fmaf(-v, v, K);
    }
    // ---- phase 0b: B-fragments, one slot per thread (tid < 512) ----
    if (tid < 512) {                         // slot: T(32) x c(4) x g2(4)
        int T = tid >> 4, c = (tid >> 2) & 3, g2 = tid & 3;
        unsigned w[4] = {0u,0u,0u,0u};
        #pragma unroll
        for (int j = 0; j < 8; ++j) {
            int n = T*32 + g2*8 + j;
            float act = 0.f;
            if (n < NN)
                act = fsig((c == 0) ? alpha[n] : colors[3*n + c - 1]);
            unsigned short us = __builtin_bit_cast(unsigned short, (_Float16)act);
            w[j>>1] |= (unsigned)us << (16*(j&1));
        }
        Lbf[T][c][g2] = (u32x4v){w[0], w[1], w[2], w[3]};
    }
    __syncthreads();

    // preload this wave's B-fragments (n-chunk owns tiles nchunk*8 .. +7)
    u32x4v BfR[TPW];
    #pragma unroll
    for (int t = 0; t < TPW; ++t)
        BfR[t] = (col < 4) ? Lbf[nchunk*TPW + t][col][g] : (u32x4v){0u,0u,0u,0u};

    // ---- phase 0c: analytic group-max. thread = (16-g chunk) x (16px group) ----
    // max_{x in [xlo,xhi]} (K' - (p*x+t)^2) = K' - (ulo*uhi>0 ? min(ulo^2,uhi^2) : 0)
    {
        const int q16 = tid & 15, chunk = tid >> 4;
        const float xlo = -1.0f + (float)(16*q16) * step;
        const float xhi = xlo + 15.f*step;
        const int nb = chunk * 16;
        float mx = -3.0e38f;
        #pragma unroll
        for (int i = 0; i < 16; ++i) {
            float p = Lp[nb+i], t = Lt[nb+i], Kp = Lk[nb+i];
            float ulo = fmaf(p, xlo, t);
            float uhi = fmaf(p, xhi, t);
            float pen = (ulo*uhi > 0.f) ? fminf(ulo*ulo, uhi*uhi) : 0.f;
            mx = fmaxf(mx, Kp - pen);
        }
        pm2[chunk][q16] = mx;
    }
    __syncthreads();
    if (tid < 16) {                          // stage 2: 64 partials -> EPS term
        float M = -3.0e38f;
        #pragma unroll
        for (int j = 0; j < 64; ++j) M = fmaxf(M, pm2[j][tid]);
        pmg[tid] = 1e-6f * ex2(M);           // EPS * 2^Mq  (ref-equivalent EPS)
    }
    // (no barrier needed before pass C: pass C doesn't read pmg; the
    //  pc4 barrier below orders pmg for the epilogue.)

    const int nbase = nchunk*256 + g*8;

    // ---- pass C: raw e = exp2(K' - u^2), MFMA accumulate (alpha,r,g,b) ----
    f32x4 C0 = {0.f,0.f,0.f,0.f}, C1 = {0.f,0.f,0.f,0.f};
    f32x4 C2 = {0.f,0.f,0.f,0.f}, C3 = {0.f,0.f,0.f,0.f};
    for (int t = 0; t < TPW; ++t) {
        int q4 = (nbase + t*32) >> 2;
        f32x4 pa = Lp4[q4], pb = Lp4[q4+1];
        f32x4 ta = Lt4[q4], tb = Lt4[q4+1];
        f32x4 ka = Lk4[q4], kb = Lk4[q4+1];
        f16x8 Bf = __builtin_bit_cast(f16x8, BfR[t]);

        u32x4v W;
        W = (u32x4v){ pk2(ev2(pa[0],ta[0],ka[0],x0), ev2(pa[1],ta[1],ka[1],x0)),
                      pk2(ev2(pa[2],ta[2],ka[2],x0), ev2(pa[3],ta[3],ka[3],x0)),
                      pk2(ev2(pb[0],tb[0],kb[0],x0), ev2(pb[1],tb[1],kb[1],x0)),
                      pk2(ev2(pb[2],tb[2],kb[2],x0), ev2(pb[3],tb[3],kb[3],x0)) };
        C0 = __builtin_amdgcn_mfma_f32_16x16x32_f16(__builtin_bit_cast(f16x8, W), Bf, C0, 0, 0, 0);
        W = (u32x4v){ pk2(ev2(pa[0],ta[0],ka[0],x1), ev2(pa[1],ta[1],ka[1],x1)),
                      pk2(ev2(pa[2],ta[2],ka[2],x1), ev2(pa[3],ta[3],ka[3],x1)),
                      pk2(ev2(pb[0],tb[0],kb[0],x1), ev2(pb[1],tb[1],kb[1],x1)),
                      pk2(ev2(pb[2],tb[2],kb[2],x1), ev2(pb[3],tb[3],kb[3],x1)) };
        C1 = __builtin_amdgcn_mfma_f32_16x16x32_f16(__builtin_bit_cast(f16x8, W), Bf, C1, 0, 0, 0);
        W = (u32x4v){ pk2(ev2(pa[0],ta[0],ka[0],x2), ev2(pa[1],ta[1],ka[1],x2)),
                      pk2(ev2(pa[2],ta[2],ka[2],x2), ev2(pa[3],ta[3],ka[3],x2)),
                      pk2(ev2(pb[0],tb[0],kb[0],x2), ev2(pb[1],tb[1],kb[1],x2)),
                      pk2(ev2(pb[2],tb[2],kb[2],x2), ev2(pb[3],tb[3],kb[3],x2)) };
        C2 = __builtin_amdgcn_mfma_f32_16x16x32_f16(__builtin_bit_cast(f16x8, W), Bf, C2, 0, 0, 0);
        W = (u32x4v){ pk2(ev2(pa[0],ta[0],ka[0],x3), ev2(pa[1],ta[1],ka[1],x3)),
                      pk2(ev2(pa[2],ta[2],ka[2],x3), ev2(pa[3],ta[3],ka[3],x3)),
                      pk2(ev2(pb[0],tb[0],kb[0],x3), ev2(pb[1],tb[1],kb[1],x3)),
                      pk2(ev2(pb[2],tb[2],kb[2],x3), ev2(pb[3],tb[3],kb[3],x3)) };
        C3 = __builtin_amdgcn_mfma_f32_16x16x32_f16(__builtin_bit_cast(f16x8, W), Bf, C3, 0, 0, 0);
    }

    // ---- epilogue: per-pixel sum over the 4 n-chunks ----
    if (col < 4) {
        float* pcf = (float*)pc4;
        #pragma unroll
        for (int i = 0; i < 4; ++i) {        // C layout: col=ch, row=4g+i
            int r0 = 4*g + i;
            pcf[(wave*64 + r0     )*4 + col] = C0[i];
            pcf[(wave*64 + r0 + 16)*4 + col] = C1[i];
            pcf[(wave*64 + r0 + 32)*4 + col] = C2[i];
            pcf[(wave*64 + r0 + 48)*4 + col] = C3[i];
        }
    }
    __syncthreads();
    if (tid < 256) {
        int px = tid;
        int pq = px >> 6, l = px & 63;
        f32x4 S = pc4[4*pq+0][l] + pc4[4*pq+1][l] + pc4[4*pq+2][l] + pc4[4*pq+3][l];
        float inv = 1.0f / (S[0] + pmg[px >> 4]);   // S: (alpha, r, g, b)
        int o = (row*256 + px) * 3;
        out[o] = S[1]*inv; out[o+1] = S[2]*inv; out[o+2] = S[3]*inv;
    }
}

extern "C" void kernel_launch(void* const* d_in, const int* in_sizes, int n_in,
                              void* d_out, int out_size, void* d_ws, size_t ws_size,
                              hipStream_t stream) {
    const float* rho    = (const float*)d_in[0];
    const float* sigma  = (const float*)d_in[1];
    const float* coords = (const float*)d_in[2];
    const float* alpha  = (const float*)d_in[3];
    const float* colors = (const float*)d_in[4];
    float* out = (float*)d_out;   // xy derived analytically (validated r8)

    // 256 rows -> 256 blocks x 1024 threads = exactly 1 block/CU
    splat_fused<<<256, 1024, 0, stream>>>(rho, sigma, coords, alpha, colors, out);
}